// Round 3
// baseline (944.185 us; speedup 1.0000x reference)
//
#include <hip/hip_runtime.h>

typedef _Float16 f16;
typedef f16  f16x8 __attribute__((ext_vector_type(8)));
typedef f16  f16x4 __attribute__((ext_vector_type(4)));
typedef float f32x4 __attribute__((ext_vector_type(4)));

#define HH 540
#define WW 960
#define HWPIX (HH*WW)

// ws layout (bytes):
//   w1p @ 0      : 64*32 f16        = 4096     [co][k(25 pad 32)]
//   w2p @ 4096   : 9*32*64 f16      = 36864    [tap][co][ci]
//   w3p @ 40960  : 9*32*32 f16      = 18432
//   w4p @ 59392  : 9*48*32 f16      = 27648    (co 37..47 zero)
//   f1  @ 131072           : 540*960*64*2 = 66,355,200
//   f2  @ 131072+66355200  : 540*960*32*2 = 33,177,600
//   f3  @ 131072           : aliases f1 (f1 dead once conv3 runs)

// ------------------------------------------------------------ weight prepack
__global__ __launch_bounds__(256) void prepack_k(const float* __restrict__ w1,
        const float* __restrict__ w2, const float* __restrict__ w3,
        const float* __restrict__ w4, f16* __restrict__ ws) {
    int i = blockIdx.x*256 + threadIdx.x;
    f16* w1p = ws;
    f16* w2p = ws + 2048;
    f16* w3p = ws + 2048 + 18432;
    f16* w4p = ws + 2048 + 18432 + 9216;
    if (i < 2048) {
        int k = i & 31, co = i >> 5;
        w1p[i] = (f16)(k < 25 ? w1[co*25 + k] : 0.f);
    } else if (i < 2048 + 18432) {
        int j = i - 2048;
        int ci = j & 63; int rest = j >> 6; int co = rest & 31; int tap = rest >> 5;
        w2p[j] = (f16)w2[(co*64 + ci)*9 + tap];
    } else if (i < 2048 + 18432 + 9216) {
        int j = i - (2048 + 18432);
        int ci = j & 31; int rest = j >> 5; int co = rest & 31; int tap = rest >> 5;
        w3p[j] = (f16)w3[(co*32 + ci)*9 + tap];
    } else if (i < 2048 + 18432 + 9216 + 13824) {
        int j = i - (2048 + 18432 + 9216);
        int ci = j & 31; int rest = j >> 5; int co = rest % 48; int tap = rest / 48;
        w4p[j] = (f16)(co < 37 ? w4[(co*32 + ci)*9 + tap] : 0.f);
    }
}

// ------------------------------------------------------------ conv1 (MFMA)
// 1->64, 5x5 pad2, PReLU. A=weights[co][k], B=pixels[px][k], K=32 (25 taps).
// C/D: row(quad*4+r4)=co, col(l16)=px  -> packed b64 stores of 4 channels.
__global__ __launch_bounds__(256) void conv1m_k(const float* __restrict__ xin,
        const f16* __restrict__ w1p, const float* __restrict__ bg,
        const float* __restrict__ pa, f16* __restrict__ f1) {
    const int tid = threadIdx.x;
    const int w = tid >> 6, lane = tid & 63, l16 = lane & 15, quad = lane >> 4;
    const int trow = blockIdx.x / 15, tcol = blockIdx.x % 15;
    const int r = trow*4 + w, x0 = tcol*64;
    const float alpha = pa[0];

    f16x8 Wf[4];
#pragma unroll
    for (int t = 0; t < 4; t++)
        Wf[t] = *(const f16x8*)&w1p[(t*16 + l16)*32 + quad*8];

    f32x4 acc[4][4];
#pragma unroll
    for (int t = 0; t < 4; t++) {
        f32x4 b4 = *(const f32x4*)&bg[t*16 + quad*4];
#pragma unroll
        for (int mt = 0; mt < 4; mt++) acc[mt][t] = b4;
    }

#pragma unroll
    for (int mt = 0; mt < 4; mt++) {
        f16x8 a;
#pragma unroll
        for (int j = 0; j < 8; j++) {
            int t = quad*8 + j;
            int ky = t / 5, kx = t - ky*5;
            int gy = r + ky - 2, gx = x0 + mt*16 + l16 + kx - 2;
            float v = 0.f;
            if (t < 25 && (unsigned)gy < (unsigned)HH && (unsigned)gx < (unsigned)WW)
                v = xin[gy*WW + gx];
            a[j] = (f16)v;
        }
#pragma unroll
        for (int t = 0; t < 4; t++)
            acc[mt][t] = __builtin_amdgcn_mfma_f32_16x16x32_f16(Wf[t], a, acc[mt][t], 0,0,0);
    }

#pragma unroll
    for (int mt = 0; mt < 4; mt++) {
        int gx = x0 + mt*16 + l16;
        size_t base = ((size_t)r*WW + gx)*64;
#pragma unroll
        for (int t = 0; t < 4; t++) {
            f16x4 h;
#pragma unroll
            for (int r4 = 0; r4 < 4; r4++) {
                float v = acc[mt][t][r4];
                v = (v >= 0.f) ? v : alpha*v;
                h[r4] = (f16)v;
            }
            *(f16x4*)&f1[base + t*16 + quad*4] = h;
        }
    }
}

// ------------------------------------------------------------ conv2/conv3 (MFMA, no LDS)
// CI->32, 3x3 pad1, PReLU. Block = 4 rows x 64 px, wave w -> row w.
// A=weights (from prepacked global, L2-broadcast), B=pixels (direct global,
// coalesced b128: 16 px x 64B dense per instruction). No LDS, no barriers.
template<int CI>
__global__ __launch_bounds__(256) void convM_k(const f16* __restrict__ fin,
        const f16* __restrict__ wp, const float* __restrict__ bg,
        const float* __restrict__ pa, f16* __restrict__ fout) {
    constexpr int KC = CI/32;
    const int tid = threadIdx.x;
    const int w = tid >> 6, lane = tid & 63, l16 = lane & 15, quad = lane >> 4;
    const int trow = blockIdx.x / 15, tcol = blockIdx.x % 15;
    const int r = trow*4 + w, x0 = tcol*64;
    const float alpha = pa[0];

    f32x4 acc[4][2];
    {
        f32x4 b0 = *(const f32x4*)&bg[quad*4];
        f32x4 b1 = *(const f32x4*)&bg[16 + quad*4];
#pragma unroll
        for (int mt = 0; mt < 4; mt++) { acc[mt][0] = b0; acc[mt][1] = b1; }
    }

#pragma unroll
    for (int dy = 0; dy < 3; dy++) {
        int gy = r + dy - 1;
        bool yok = (unsigned)gy < (unsigned)HH;
        const f16* rowp = fin + (size_t)gy*WW*CI;
#pragma unroll
        for (int dx = 0; dx < 3; dx++) {
            int tap = dy*3 + dx;
            f16x8 Wf[KC][2];
#pragma unroll
            for (int kc = 0; kc < KC; kc++)
#pragma unroll
                for (int t = 0; t < 2; t++)
                    Wf[kc][t] = *(const f16x8*)&wp[(tap*32 + t*16 + l16)*CI + kc*32 + quad*8];
#pragma unroll
            for (int mt = 0; mt < 4; mt++) {
                int gx = x0 + mt*16 + l16 + dx - 1;
                bool ok = yok && (unsigned)gx < (unsigned)WW;
                const f16* pp = rowp + (size_t)gx*CI + quad*8;
#pragma unroll
                for (int kc = 0; kc < KC; kc++) {
                    f16x8 a = {};
                    if (ok) a = *(const f16x8*)(pp + kc*32);
#pragma unroll
                    for (int t = 0; t < 2; t++)
                        acc[mt][t] = __builtin_amdgcn_mfma_f32_16x16x32_f16(Wf[kc][t], a, acc[mt][t], 0,0,0);
                }
            }
        }
    }

#pragma unroll
    for (int mt = 0; mt < 4; mt++) {
        int gx = x0 + mt*16 + l16;
        size_t base = ((size_t)r*WW + gx)*32;
#pragma unroll
        for (int t = 0; t < 2; t++) {
            f16x4 h;
#pragma unroll
            for (int r4 = 0; r4 < 4; r4++) {
                float v = acc[mt][t][r4];
                v = (v >= 0.f) ? v : alpha*v;
                h[r4] = (f16)v;
            }
            *(f16x4*)&fout[base + t*16 + quad*4] = h;
        }
    }
}

// ------------------------------------------------------------ conv4 (MFMA) + fused head
// 32->37 (pad 48 = 3 n-tiles), 3x3 pad1, bias, no act; head fused.
// One LDS round-trip for the per-pixel head; stride 42 f32 (bank stride 10).
__global__ __launch_bounds__(256) void conv4m_k(const f16* __restrict__ fin,
        const f16* __restrict__ wp, const float* __restrict__ bg,
        float* __restrict__ outp) {
    __shared__ float olds[256*42];
    const int tid = threadIdx.x;
    const int w = tid >> 6, lane = tid & 63, l16 = lane & 15, quad = lane >> 4;
    const int trow = blockIdx.x / 15, tcol = blockIdx.x % 15;
    const int r = trow*4 + w, x0 = tcol*64;

    f32x4 acc[4][3];
    {
        f32x4 b0 = *(const f32x4*)&bg[quad*4];
        f32x4 b1 = *(const f32x4*)&bg[16 + quad*4];
        f32x4 b2;
#pragma unroll
        for (int r4 = 0; r4 < 4; r4++) {
            int co = 32 + quad*4 + r4;
            b2[r4] = (co < 37) ? bg[co] : 0.f;
        }
#pragma unroll
        for (int mt = 0; mt < 4; mt++) { acc[mt][0] = b0; acc[mt][1] = b1; acc[mt][2] = b2; }
    }

#pragma unroll
    for (int dy = 0; dy < 3; dy++) {
        int gy = r + dy - 1;
        bool yok = (unsigned)gy < (unsigned)HH;
        const f16* rowp = fin + (size_t)gy*WW*32;
#pragma unroll
        for (int dx = 0; dx < 3; dx++) {
            int tap = dy*3 + dx;
            f16x8 Wf[3];
#pragma unroll
            for (int t = 0; t < 3; t++)
                Wf[t] = *(const f16x8*)&wp[(tap*48 + t*16 + l16)*32 + quad*8];
#pragma unroll
            for (int mt = 0; mt < 4; mt++) {
                int gx = x0 + mt*16 + l16 + dx - 1;
                bool ok = yok && (unsigned)gx < (unsigned)WW;
                f16x8 a = {};
                if (ok) a = *(const f16x8*)(rowp + (size_t)gx*32 + quad*8);
#pragma unroll
                for (int t = 0; t < 3; t++)
                    acc[mt][t] = __builtin_amdgcn_mfma_f32_16x16x32_f16(Wf[t], a, acc[mt][t], 0,0,0);
            }
        }
    }

    // write W (37 ch, fp32) to LDS [px][42]
#pragma unroll
    for (int mt = 0; mt < 4; mt++) {
        float* dst = &olds[(w*64 + mt*16 + l16)*42];
#pragma unroll
        for (int t = 0; t < 3; t++) {
            if (t < 2 || quad < 2) {
                int cb = t*16 + quad*4;
                *(float2*)&dst[cb]   = make_float2(acc[mt][t][0], acc[mt][t][1]);
                *(float2*)&dst[cb+2] = make_float2(acc[mt][t][2], acc[mt][t][3]);
            }
        }
    }
    __syncthreads();

    // head: 1 px/thread. k0=(-.25,.25) k1=(.25,.25) k2=(-.25,-.25) k3=(.25,-.25)
    {
        int px = tid;
        int rr = px >> 6, xx = px & 63;
        const float* Wp = &olds[px*42];
        float base = Wp[36];
        float o0 = base, o1 = base, o2 = base, o3 = base;
#pragma unroll
        for (int j = 0; j < 12; j++) {
            float u  = Wp[2*j];
            float v  = Wp[2*j+1];
            float w1 = Wp[24+j];
            float s = 0.25f*(u+v);
            float d = 0.25f*(v-u);
            o0 += fmaxf(d, 0.f)*w1;
            o1 += fmaxf(s, 0.f)*w1;
            o2 += fmaxf(-s, 0.f)*w1;
            o3 += fmaxf(-d, 0.f)*w1;
        }
        int gy = trow*4 + rr, gx = x0 + xx;
        *(float2*)(outp + (size_t)(2*gy)*(2*WW) + 2*gx)   = make_float2(o0, o1);
        *(float2*)(outp + (size_t)(2*gy+1)*(2*WW) + 2*gx) = make_float2(o2, o3);
    }
}

extern "C" void kernel_launch(void* const* d_in, const int* in_sizes, int n_in,
                              void* d_out, int out_size, void* d_ws, size_t ws_size,
                              hipStream_t stream) {
    const float* x  = (const float*)d_in[0];
    const float* w1 = (const float*)d_in[1];
    const float* b1 = (const float*)d_in[2];
    const float* w2 = (const float*)d_in[3];
    const float* b2 = (const float*)d_in[4];
    const float* w3 = (const float*)d_in[5];
    const float* b3 = (const float*)d_in[6];
    const float* w4 = (const float*)d_in[7];
    const float* b4 = (const float*)d_in[8];
    const float* pa = (const float*)d_in[9];
    float* outp = (float*)d_out;

    char* ws = (char*)d_ws;
    f16* wpk = (f16*)ws;
    const f16* w1p = wpk;
    const f16* w2p = wpk + 2048;
    const f16* w3p = wpk + 2048 + 18432;
    const f16* w4p = wpk + 2048 + 18432 + 9216;
    f16* f1 = (f16*)(ws + 131072);                  // 66,355,200 B
    f16* f2 = (f16*)(ws + 131072 + 66355200);       // 33,177,600 B
    f16* f3 = f1;                                   // alias: f1 dead by conv3

    prepack_k<<<dim3((43520 + 255)/256), 256, 0, stream>>>(w1, w2, w3, w4, wpk);

    const int NT = 2025;   // (540/4) * (960/64)
    for (int b = 0; b < 4; b++) {
        conv1m_k<<<dim3(NT), 256, 0, stream>>>(x + (size_t)b*HWPIX, w1p, b1, pa, f1);
        convM_k<64><<<dim3(NT), 256, 0, stream>>>(f1, w2p, b2, pa, f2);
        convM_k<32><<<dim3(NT), 256, 0, stream>>>(f2, w3p, b3, pa, f3);
        conv4m_k<<<dim3(NT), 256, 0, stream>>>(f3, w4p, b4, outp + (size_t)b*4*HWPIX);
    }
}

// Round 4
// 653.718 us; speedup vs baseline: 1.4443x; 1.4443x over previous
//
#include <hip/hip_runtime.h>

typedef _Float16 f16;
typedef f16  f16x8 __attribute__((ext_vector_type(8)));
typedef f16  f16x4 __attribute__((ext_vector_type(4)));
typedef float f32x4 __attribute__((ext_vector_type(4)));

#define HH 540
#define WW 960
#define HWPIX (HH*WW)

// ws layout (bytes):
//   wpk @ 0: prepacked f16 weights (w1p 4096 | w2p 36864 | w3p 18432 | w4p 27648)
//   f1  @ 131072            : 540*960*64*2 = 66,355,200
//   f2  @ 131072+66355200   : 540*960*32*2 = 33,177,600
//   f3  @ 131072            : aliases f1 (f1 dead once conv3 runs; stream-ordered)

// ------------------------------------------------------------ weight prepack
__global__ __launch_bounds__(256) void prepack_k(const float* __restrict__ w1,
        const float* __restrict__ w2, const float* __restrict__ w3,
        const float* __restrict__ w4, f16* __restrict__ ws) {
    int i = blockIdx.x*256 + threadIdx.x;
    f16* w1p = ws;
    f16* w2p = ws + 2048;
    f16* w3p = ws + 2048 + 18432;
    f16* w4p = ws + 2048 + 18432 + 9216;
    if (i < 2048) {
        int k = i & 31, co = i >> 5;
        w1p[i] = (f16)(k < 25 ? w1[co*25 + k] : 0.f);
    } else if (i < 2048 + 18432) {
        int j = i - 2048;
        int ci = j & 63; int rest = j >> 6; int co = rest & 31; int tap = rest >> 5;
        w2p[j] = (f16)w2[(co*64 + ci)*9 + tap];
    } else if (i < 2048 + 18432 + 9216) {
        int j = i - (2048 + 18432);
        int ci = j & 31; int rest = j >> 5; int co = rest & 31; int tap = rest >> 5;
        w3p[j] = (f16)w3[(co*32 + ci)*9 + tap];
    } else if (i < 2048 + 18432 + 9216 + 13824) {
        int j = i - (2048 + 18432 + 9216);
        int ci = j & 31; int rest = j >> 5; int co = rest % 48; int tap = rest / 48;
        w4p[j] = (f16)(co < 37 ? w4[(co*32 + ci)*9 + tap] : 0.f);
    }
}

// ------------------------------------------------------------ conv1 (MFMA)
// 1->64, 5x5 pad2, PReLU. A=weights[co][k(25 pad 32)], B=pixels. LDS-staged x tile.
__global__ __launch_bounds__(256) void conv1m_k(const float* __restrict__ xin,
        const f16* __restrict__ w1p, const float* __restrict__ bg,
        const float* __restrict__ pa, f16* __restrict__ f1) {
    __shared__ float tile[8*72];   // rows ytile-2..ytile+5, cols x0-2..x0+69
    const int tid = threadIdx.x;
    const int w = tid >> 6, lane = tid & 63, l16 = lane & 15, quad = lane >> 4;
    const int trow = blockIdx.x / 15, tcol = blockIdx.x % 15;
    const int r = trow*4 + w, x0 = tcol*64;
    const float alpha = pa[0];

    for (int i = tid; i < 8*72; i += 256) {
        int rr = i / 72, xl = i - rr*72;
        int gy = trow*4 + rr - 2, gx = x0 + xl - 2;
        float v = 0.f;
        if ((unsigned)gy < (unsigned)HH && (unsigned)gx < (unsigned)WW)
            v = xin[gy*WW + gx];
        tile[i] = v;
    }

    f16x8 Wf[4];
#pragma unroll
    for (int t = 0; t < 4; t++)
        Wf[t] = *(const f16x8*)&w1p[(t*16 + l16)*32 + quad*8];

    f32x4 acc[4][4];
#pragma unroll
    for (int t = 0; t < 4; t++) {
        f32x4 b4 = *(const f32x4*)&bg[t*16 + quad*4];
#pragma unroll
        for (int mt = 0; mt < 4; mt++) acc[mt][t] = b4;
    }

    // per-j LDS offsets: tap t = quad*8+j -> (ky,kx); addr = (w+ky)*72 + l16 + kx
    int offj[8];
    bool okj[8];
#pragma unroll
    for (int j = 0; j < 8; j++) {
        int t = quad*8 + j;
        int ky = t / 5, kx = t - ky*5;
        offj[j] = (w + ky)*72 + l16 + kx;
        okj[j] = (t < 25);
    }
    __syncthreads();

#pragma unroll
    for (int mt = 0; mt < 4; mt++) {
        f16x8 a;
#pragma unroll
        for (int j = 0; j < 8; j++)
            a[j] = okj[j] ? (f16)tile[offj[j] + mt*16] : (f16)0.f;
#pragma unroll
        for (int t = 0; t < 4; t++)
            acc[mt][t] = __builtin_amdgcn_mfma_f32_16x16x32_f16(Wf[t], a, acc[mt][t], 0,0,0);
    }

#pragma unroll
    for (int mt = 0; mt < 4; mt++) {
        int gx = x0 + mt*16 + l16;
        size_t base = ((size_t)r*WW + gx)*64;
#pragma unroll
        for (int t = 0; t < 4; t++) {
            f16x4 h;
#pragma unroll
            for (int r4 = 0; r4 < 4; r4++) {
                float v = acc[mt][t][r4];
                v = (v >= 0.f) ? v : alpha*v;
                h[r4] = (f16)v;
            }
            *(f16x4*)&f1[base + t*16 + quad*4] = h;
        }
    }
}

// ------------------------------------------------------------ conv2/conv3 (MFMA)
// CI->32, 3x3 pad1, PReLU. Block = 4 rows x 64 px, wave w -> row w.
// Weights: prepacked f16 [tap][co][ci] -> registers once per block (L2 broadcast).
// Input: LDS tile 6x66 px, CIP=CI+8 pad (lane stride 144/80B -> 2-way = free).
// Epilogue: direct packed f16x4 global stores from acc. Two barriers total... one.
template<int CI>
__global__ __launch_bounds__(256, 2) void convM_k(const f16* __restrict__ fin,
        const f16* __restrict__ wp, const float* __restrict__ bg,
        const float* __restrict__ pa, f16* __restrict__ fout) {
    constexpr int KC  = CI/32;
    constexpr int CIP = CI + 8;
    constexpr int C16 = CI/8;                  // 16B chunks per pixel
    constexpr int CHUNKS = 6*66*C16;
    __shared__ __align__(16) f16 tile[6*66*CIP];

    const int tid = threadIdx.x;
    const int w = tid >> 6, lane = tid & 63, l16 = lane & 15, quad = lane >> 4;
    const int trow = blockIdx.x / 15, tcol = blockIdx.x % 15;
    const int ytile = trow*4, x0 = tcol*64, r = ytile + w;
    const float alpha = pa[0];

    // stage input tile (zero halo)
#pragma unroll
    for (int it = 0; it < (CHUNKS + 255)/256; it++) {
        int i = it*256 + tid;
        if (i < CHUNKS) {
            int c8 = i % C16; int rest = i / C16; int xl = rest % 66; int rr = rest / 66;
            int gy = ytile + rr - 1, gx = x0 + xl - 1;
            uint4 v = make_uint4(0u,0u,0u,0u);
            if ((unsigned)gy < (unsigned)HH && (unsigned)gx < (unsigned)WW)
                v = *(const uint4*)&fin[((size_t)gy*WW + gx)*CI + c8*8];
            *(uint4*)&tile[(rr*66 + xl)*CIP + c8*8] = v;
        }
    }

    // weights -> registers (once per block)
    f16x8 Wf[9][KC][2];
#pragma unroll
    for (int tap = 0; tap < 9; tap++)
#pragma unroll
        for (int kc = 0; kc < KC; kc++)
#pragma unroll
            for (int t = 0; t < 2; t++)
                Wf[tap][kc][t] = *(const f16x8*)&wp[(tap*32 + t*16 + l16)*CI + kc*32 + quad*8];

    f32x4 acc[4][2];
    {
        f32x4 b0 = *(const f32x4*)&bg[quad*4];
        f32x4 b1 = *(const f32x4*)&bg[16 + quad*4];
#pragma unroll
        for (int p = 0; p < 4; p++) { acc[p][0] = b0; acc[p][1] = b1; }
    }
    __syncthreads();

#pragma unroll
    for (int p = 0; p < 4; p++) {
#pragma unroll
        for (int dy = 0; dy < 3; dy++) {
            const f16* base = &tile[((w + dy)*66 + p*16 + l16)*CIP + quad*8];
#pragma unroll
            for (int dx = 0; dx < 3; dx++)
#pragma unroll
                for (int kc = 0; kc < KC; kc++) {
                    f16x8 b = *(const f16x8*)&base[dx*CIP + kc*32];
                    acc[p][0] = __builtin_amdgcn_mfma_f32_16x16x32_f16(Wf[dy*3+dx][kc][0], b, acc[p][0], 0,0,0);
                    acc[p][1] = __builtin_amdgcn_mfma_f32_16x16x32_f16(Wf[dy*3+dx][kc][1], b, acc[p][1], 0,0,0);
                }
        }
    }

#pragma unroll
    for (int p = 0; p < 4; p++) {
        int gx = x0 + p*16 + l16;
        size_t bo = ((size_t)r*WW + gx)*32;
#pragma unroll
        for (int t = 0; t < 2; t++) {
            f16x4 h;
#pragma unroll
            for (int r4 = 0; r4 < 4; r4++) {
                float v = acc[p][t][r4];
                v = (v >= 0.f) ? v : alpha*v;
                h[r4] = (f16)v;
            }
            *(f16x4*)&fout[bo + t*16 + quad*4] = h;
        }
    }
}

// ------------------------------------------------------------ conv4 (MFMA) + fused head
// 32->37 (pad 48), 3x3 pad1, bias, no act; fused pixel head via LDS round-trip.
__global__ __launch_bounds__(256, 2) void conv4m_k(const f16* __restrict__ fin,
        const f16* __restrict__ wp, const float* __restrict__ bg,
        float* __restrict__ outp) {
    constexpr int CI = 32, CIP = 40, C16 = 4, CHUNKS = 6*66*C16;
    __shared__ __align__(16) char smem[256*42*4];   // 43008B >= tile 31680B
    f16*   tile = (f16*)smem;
    float* olds = (float*)smem;

    const int tid = threadIdx.x;
    const int w = tid >> 6, lane = tid & 63, l16 = lane & 15, quad = lane >> 4;
    const int trow = blockIdx.x / 15, tcol = blockIdx.x % 15;
    const int ytile = trow*4, x0 = tcol*64;

#pragma unroll
    for (int it = 0; it < (CHUNKS + 255)/256; it++) {
        int i = it*256 + tid;
        if (i < CHUNKS) {
            int c8 = i % C16; int rest = i / C16; int xl = rest % 66; int rr = rest / 66;
            int gy = ytile + rr - 1, gx = x0 + xl - 1;
            uint4 v = make_uint4(0u,0u,0u,0u);
            if ((unsigned)gy < (unsigned)HH && (unsigned)gx < (unsigned)WW)
                v = *(const uint4*)&fin[((size_t)gy*WW + gx)*CI + c8*8];
            *(uint4*)&tile[(rr*66 + xl)*CIP + c8*8] = v;
        }
    }

    f16x8 Wf[9][3];
#pragma unroll
    for (int tap = 0; tap < 9; tap++)
#pragma unroll
        for (int t = 0; t < 3; t++)
            Wf[tap][t] = *(const f16x8*)&wp[(tap*48 + t*16 + l16)*32 + quad*8];

    f32x4 acc[4][3];
    {
        f32x4 b0 = *(const f32x4*)&bg[quad*4];
        f32x4 b1 = *(const f32x4*)&bg[16 + quad*4];
        f32x4 b2;
#pragma unroll
        for (int r4 = 0; r4 < 4; r4++) {
            int co = 32 + quad*4 + r4;
            b2[r4] = (co < 37) ? bg[co] : 0.f;
        }
#pragma unroll
        for (int p = 0; p < 4; p++) { acc[p][0] = b0; acc[p][1] = b1; acc[p][2] = b2; }
    }
    __syncthreads();

#pragma unroll
    for (int p = 0; p < 4; p++) {
#pragma unroll
        for (int dy = 0; dy < 3; dy++) {
            const f16* base = &tile[((w + dy)*66 + p*16 + l16)*CIP + quad*8];
#pragma unroll
            for (int dx = 0; dx < 3; dx++) {
                f16x8 b = *(const f16x8*)&base[dx*CIP];
#pragma unroll
                for (int t = 0; t < 3; t++)
                    acc[p][t] = __builtin_amdgcn_mfma_f32_16x16x32_f16(Wf[dy*3+dx][t], b, acc[p][t], 0,0,0);
            }
        }
    }
    __syncthreads();   // tile dead; reuse as olds

    // W (37ch fp32) -> LDS [px][42]
#pragma unroll
    for (int p = 0; p < 4; p++) {
        float* dst = &olds[(w*64 + p*16 + l16)*42];
#pragma unroll
        for (int t = 0; t < 3; t++) {
            if (t < 2 || quad < 2) {
                int cb = t*16 + quad*4;
                *(float2*)&dst[cb]   = make_float2(acc[p][t][0], acc[p][t][1]);
                *(float2*)&dst[cb+2] = make_float2(acc[p][t][2], acc[p][t][3]);
            }
        }
    }
    __syncthreads();

    // head: 1 px/thread. k0=(-.25,.25) k1=(.25,.25) k2=(-.25,-.25) k3=(.25,-.25)
    {
        int px = tid;
        int rr = px >> 6, xx = px & 63;
        const float* Wp = &olds[px*42];
        float base = Wp[36];
        float o0 = base, o1 = base, o2 = base, o3 = base;
#pragma unroll
        for (int j = 0; j < 12; j++) {
            float u  = Wp[2*j];
            float v  = Wp[2*j+1];
            float w1 = Wp[24+j];
            float s = 0.25f*(u+v);
            float d = 0.25f*(v-u);
            o0 += fmaxf(d, 0.f)*w1;
            o1 += fmaxf(s, 0.f)*w1;
            o2 += fmaxf(-s, 0.f)*w1;
            o3 += fmaxf(-d, 0.f)*w1;
        }
        int gy = trow*4 + rr, gx = x0 + xx;
        *(float2*)(outp + (size_t)(2*gy)*(2*WW) + 2*gx)   = make_float2(o0, o1);
        *(float2*)(outp + (size_t)(2*gy+1)*(2*WW) + 2*gx) = make_float2(o2, o3);
    }
}

extern "C" void kernel_launch(void* const* d_in, const int* in_sizes, int n_in,
                              void* d_out, int out_size, void* d_ws, size_t ws_size,
                              hipStream_t stream) {
    const float* x  = (const float*)d_in[0];
    const float* w1 = (const float*)d_in[1];
    const float* b1 = (const float*)d_in[2];
    const float* w2 = (const float*)d_in[3];
    const float* b2 = (const float*)d_in[4];
    const float* w3 = (const float*)d_in[5];
    const float* b3 = (const float*)d_in[6];
    const float* w4 = (const float*)d_in[7];
    const float* b4 = (const float*)d_in[8];
    const float* pa = (const float*)d_in[9];
    float* outp = (float*)d_out;

    char* ws = (char*)d_ws;
    f16* wpk = (f16*)ws;
    const f16* w1p = wpk;
    const f16* w2p = wpk + 2048;
    const f16* w3p = wpk + 2048 + 18432;
    const f16* w4p = wpk + 2048 + 18432 + 9216;
    f16* f1 = (f16*)(ws + 131072);
    f16* f2 = (f16*)(ws + 131072 + 66355200);
    f16* f3 = f1;   // alias: f1 dead by conv3 (stream-ordered)

    prepack_k<<<dim3(170), 256, 0, stream>>>(w1, w2, w3, w4, wpk);

    const int NT = 2025;   // (540/4) * (960/64)
    for (int b = 0; b < 4; b++) {
        conv1m_k<<<dim3(NT), 256, 0, stream>>>(x + (size_t)b*HWPIX, w1p, b1, pa, f1);
        convM_k<64><<<dim3(NT), 256, 0, stream>>>(f1, w2p, b2, pa, f2);
        convM_k<32><<<dim3(NT), 256, 0, stream>>>(f2, w3p, b3, pa, f3);
        conv4m_k<<<dim3(NT), 256, 0, stream>>>(f3, w4p, b4, outp + (size_t)b*4*HWPIX);
    }
}

// Round 5
// 616.623 us; speedup vs baseline: 1.5312x; 1.0602x over previous
//
#include <hip/hip_runtime.h>

typedef _Float16 f16;
typedef f16  f16x8 __attribute__((ext_vector_type(8)));
typedef f16  f16x4 __attribute__((ext_vector_type(4)));
typedef float f32x4 __attribute__((ext_vector_type(4)));

#define HH 540
#define WW 960
#define HWPIX (HH*WW)

// ws layout (bytes):
//   wpk @ 0: prepacked f16 weights (w1p 4096 | w2p 36864 | w3p 18432 | w4p 27648)
//   f1  @ 131072            : 540*960*64*2 = 66,355,200
//   f2  @ 131072+66355200   : 540*960*32*2 = 33,177,600
//   f3  @ 131072            : aliases f1 (f1 dead once conv3 runs; stream-ordered)

// ------------------------------------------------------------ weight prepack
__global__ __launch_bounds__(256) void prepack_k(const float* __restrict__ w1,
        const float* __restrict__ w2, const float* __restrict__ w3,
        const float* __restrict__ w4, f16* __restrict__ ws) {
    int i = blockIdx.x*256 + threadIdx.x;
    f16* w1p = ws;
    f16* w2p = ws + 2048;
    f16* w3p = ws + 2048 + 18432;
    f16* w4p = ws + 2048 + 18432 + 9216;
    if (i < 2048) {
        int k = i & 31, co = i >> 5;
        w1p[i] = (f16)(k < 25 ? w1[co*25 + k] : 0.f);
    } else if (i < 2048 + 18432) {
        int j = i - 2048;
        int ci = j & 63; int rest = j >> 6; int co = rest & 31; int tap = rest >> 5;
        w2p[j] = (f16)w2[(co*64 + ci)*9 + tap];
    } else if (i < 2048 + 18432 + 9216) {
        int j = i - (2048 + 18432);
        int ci = j & 31; int rest = j >> 5; int co = rest & 31; int tap = rest >> 5;
        w3p[j] = (f16)w3[(co*32 + ci)*9 + tap];
    } else if (i < 2048 + 18432 + 9216 + 13824) {
        int j = i - (2048 + 18432 + 9216);
        int ci = j & 31; int rest = j >> 5; int co = rest % 48; int tap = rest / 48;
        w4p[j] = (f16)(co < 37 ? w4[(co*32 + ci)*9 + tap] : 0.f);
    }
}

// ------------------------------------------------------------ conv1 (MFMA)
// 1->64, 5x5 pad2, PReLU. A=weights[co][k(25 pad 32)], B=pixels. LDS-staged x tile.
__global__ __launch_bounds__(256, 4) void conv1m_k(const float* __restrict__ xin,
        const f16* __restrict__ w1p, const float* __restrict__ bg,
        const float* __restrict__ pa, f16* __restrict__ f1) {
    __shared__ float tile[8*72];   // rows ytile-2..ytile+5, cols x0-2..x0+69
    const int tid = threadIdx.x;
    const int w = tid >> 6, lane = tid & 63, l16 = lane & 15, quad = lane >> 4;
    const int trow = blockIdx.x / 15, tcol = blockIdx.x % 15;
    const int r = trow*4 + w, x0 = tcol*64;
    const float alpha = pa[0];

    for (int i = tid; i < 8*72; i += 256) {
        int rr = i / 72, xl = i - rr*72;
        int gy = trow*4 + rr - 2, gx = x0 + xl - 2;
        float v = 0.f;
        if ((unsigned)gy < (unsigned)HH && (unsigned)gx < (unsigned)WW)
            v = xin[gy*WW + gx];
        tile[i] = v;
    }

    f16x8 Wf[4];
#pragma unroll
    for (int t = 0; t < 4; t++)
        Wf[t] = *(const f16x8*)&w1p[(t*16 + l16)*32 + quad*8];

    f32x4 acc[4][4];
#pragma unroll
    for (int t = 0; t < 4; t++) {
        f32x4 b4 = *(const f32x4*)&bg[t*16 + quad*4];
#pragma unroll
        for (int mt = 0; mt < 4; mt++) acc[mt][t] = b4;
    }

    int offj[8];
    bool okj[8];
#pragma unroll
    for (int j = 0; j < 8; j++) {
        int t = quad*8 + j;
        int ky = t / 5, kx = t - ky*5;
        offj[j] = (w + ky)*72 + l16 + kx;
        okj[j] = (t < 25);
    }
    __syncthreads();

#pragma unroll
    for (int mt = 0; mt < 4; mt++) {
        f16x8 a;
#pragma unroll
        for (int j = 0; j < 8; j++)
            a[j] = okj[j] ? (f16)tile[offj[j] + mt*16] : (f16)0.f;
#pragma unroll
        for (int t = 0; t < 4; t++)
            acc[mt][t] = __builtin_amdgcn_mfma_f32_16x16x32_f16(Wf[t], a, acc[mt][t], 0,0,0);
    }

#pragma unroll
    for (int mt = 0; mt < 4; mt++) {
        int gx = x0 + mt*16 + l16;
        size_t base = ((size_t)r*WW + gx)*64;
#pragma unroll
        for (int t = 0; t < 4; t++) {
            f16x4 h;
#pragma unroll
            for (int r4 = 0; r4 < 4; r4++) {
                float v = acc[mt][t][r4];
                v = (v >= 0.f) ? v : alpha*v;
                h[r4] = (f16)v;
            }
            *(f16x4*)&f1[base + t*16 + quad*4] = h;
        }
    }
}

// ------------------------------------------------------------ conv2/conv3 (MFMA)
// CI->32, 3x3 pad1, PReLU. Block = 4 rows x 64 px, wave w -> row w.
// LDS tile XOR-swizzled (chunk c8 of pixel xl at c8^(xl&(C16-1))): no pad,
// conflict-free, conv2 tile 50.7KB -> 3 blocks/CU.
// Weights: tap-outer (dy not unrolled) -> only 3 taps of frags live (no spills).
template<int CI, int MINW>
__global__ __launch_bounds__(256, MINW) void convM_k(const f16* __restrict__ fin,
        const f16* __restrict__ wp, const float* __restrict__ bg,
        const float* __restrict__ pa, f16* __restrict__ fout) {
    constexpr int KC  = CI/32;
    constexpr int C16 = CI/8;            // 16B chunks per pixel
    constexpr int SWZ = C16 - 1;
    constexpr int CHUNKS = 6*66*C16;
    __shared__ __align__(16) f16 tile[6*66*CI];

    const int tid = threadIdx.x;
    const int w = tid >> 6, lane = tid & 63, l16 = lane & 15, quad = lane >> 4;
    const int trow = blockIdx.x / 15, tcol = blockIdx.x % 15;
    const int ytile = trow*4, x0 = tcol*64, r = ytile + w;
    const float alpha = pa[0];

    // stage input tile (zero halo), swizzled
#pragma unroll
    for (int it = 0; it < (CHUNKS + 255)/256; it++) {
        int i = it*256 + tid;
        if (i < CHUNKS) {
            int c8 = i & SWZ; int rest = i / C16; int xl = rest % 66; int rr = rest / 66;
            int gy = ytile + rr - 1, gx = x0 + xl - 1;
            uint4 v = make_uint4(0u,0u,0u,0u);
            if ((unsigned)gy < (unsigned)HH && (unsigned)gx < (unsigned)WW)
                v = *(const uint4*)&fin[((size_t)gy*WW + gx)*CI + c8*8];
            *(uint4*)&tile[(rr*66 + xl)*CI + ((c8 ^ (xl & SWZ))*8)] = v;
        }
    }

    f32x4 acc[4][2];
    {
        f32x4 b0 = *(const f32x4*)&bg[quad*4];
        f32x4 b1 = *(const f32x4*)&bg[16 + quad*4];
#pragma unroll
        for (int p = 0; p < 4; p++) { acc[p][0] = b0; acc[p][1] = b1; }
    }

    // precomputed column offsets: xl = p*16 + l16 + dx; (xl&SWZ) == ((l16+dx)&SWZ)
    int cix[3][KC];
#pragma unroll
    for (int dx = 0; dx < 3; dx++)
#pragma unroll
        for (int kc = 0; kc < KC; kc++)
            cix[dx][kc] = (l16 + dx)*CI + (((kc*4 + quad) ^ ((l16 + dx) & SWZ))*8);

    __syncthreads();

#pragma unroll 1
    for (int dy = 0; dy < 3; dy++) {
        // weights for this dy's 3 taps (L2-hot broadcast loads)
        f16x8 Wf[3][KC][2];
#pragma unroll
        for (int dx = 0; dx < 3; dx++)
#pragma unroll
            for (int kc = 0; kc < KC; kc++)
#pragma unroll
                for (int t = 0; t < 2; t++)
                    Wf[dx][kc][t] = *(const f16x8*)&wp[((dy*3+dx)*32 + t*16 + l16)*CI + kc*32 + quad*8];
        const f16* rowb = &tile[(w + dy)*66*CI];
#pragma unroll
        for (int p = 0; p < 4; p++) {
#pragma unroll
            for (int dx = 0; dx < 3; dx++)
#pragma unroll
                for (int kc = 0; kc < KC; kc++) {
                    f16x8 b = *(const f16x8*)&rowb[p*16*CI + cix[dx][kc]];
                    acc[p][0] = __builtin_amdgcn_mfma_f32_16x16x32_f16(Wf[dx][kc][0], b, acc[p][0], 0,0,0);
                    acc[p][1] = __builtin_amdgcn_mfma_f32_16x16x32_f16(Wf[dx][kc][1], b, acc[p][1], 0,0,0);
                }
        }
    }

#pragma unroll
    for (int p = 0; p < 4; p++) {
        int gx = x0 + p*16 + l16;
        size_t bo = ((size_t)r*WW + gx)*32;
#pragma unroll
        for (int t = 0; t < 2; t++) {
            f16x4 h;
#pragma unroll
            for (int r4 = 0; r4 < 4; r4++) {
                float v = acc[p][t][r4];
                v = (v >= 0.f) ? v : alpha*v;
                h[r4] = (f16)v;
            }
            *(f16x4*)&fout[bo + t*16 + quad*4] = h;
        }
    }
}

// ------------------------------------------------------------ conv4 (MFMA) + fused head
// 32->37 (pad 48), 3x3 pad1, bias, no act; fused pixel head via LDS round-trip.
__global__ __launch_bounds__(256, 3) void conv4m_k(const f16* __restrict__ fin,
        const f16* __restrict__ wp, const float* __restrict__ bg,
        float* __restrict__ outp) {
    constexpr int CI = 32, C16 = 4, SWZ = 3, CHUNKS = 6*66*C16;
    __shared__ __align__(16) char smem[256*42*4];   // 43008B >= tile 25344B
    f16*   tile = (f16*)smem;
    float* olds = (float*)smem;

    const int tid = threadIdx.x;
    const int w = tid >> 6, lane = tid & 63, l16 = lane & 15, quad = lane >> 4;
    const int trow = blockIdx.x / 15, tcol = blockIdx.x % 15;
    const int ytile = trow*4, x0 = tcol*64;

#pragma unroll
    for (int it = 0; it < (CHUNKS + 255)/256; it++) {
        int i = it*256 + tid;
        if (i < CHUNKS) {
            int c8 = i & SWZ; int rest = i >> 2; int xl = rest % 66; int rr = rest / 66;
            int gy = ytile + rr - 1, gx = x0 + xl - 1;
            uint4 v = make_uint4(0u,0u,0u,0u);
            if ((unsigned)gy < (unsigned)HH && (unsigned)gx < (unsigned)WW)
                v = *(const uint4*)&fin[((size_t)gy*WW + gx)*CI + c8*8];
            *(uint4*)&tile[(rr*66 + xl)*CI + ((c8 ^ (xl & SWZ))*8)] = v;
        }
    }

    f32x4 acc[4][3];
    {
        f32x4 b0 = *(const f32x4*)&bg[quad*4];
        f32x4 b1 = *(const f32x4*)&bg[16 + quad*4];
        f32x4 b2;
#pragma unroll
        for (int r4 = 0; r4 < 4; r4++) {
            int co = 32 + quad*4 + r4;
            b2[r4] = (co < 37) ? bg[co] : 0.f;
        }
#pragma unroll
        for (int p = 0; p < 4; p++) { acc[p][0] = b0; acc[p][1] = b1; acc[p][2] = b2; }
    }

    int cix[3];
#pragma unroll
    for (int dx = 0; dx < 3; dx++)
        cix[dx] = (l16 + dx)*CI + ((quad ^ ((l16 + dx) & SWZ))*8);

    __syncthreads();

#pragma unroll 1
    for (int dy = 0; dy < 3; dy++) {
        f16x8 Wf[3][3];
#pragma unroll
        for (int dx = 0; dx < 3; dx++)
#pragma unroll
            for (int t = 0; t < 3; t++)
                Wf[dx][t] = *(const f16x8*)&wp[((dy*3+dx)*48 + t*16 + l16)*32 + quad*8];
        const f16* rowb = &tile[(w + dy)*66*CI];
#pragma unroll
        for (int p = 0; p < 4; p++) {
#pragma unroll
            for (int dx = 0; dx < 3; dx++) {
                f16x8 b = *(const f16x8*)&rowb[p*16*CI + cix[dx]];
#pragma unroll
                for (int t = 0; t < 3; t++)
                    acc[p][t] = __builtin_amdgcn_mfma_f32_16x16x32_f16(Wf[dx][t], b, acc[p][t], 0,0,0);
            }
        }
    }
    __syncthreads();   // tile dead; reuse as olds

    // W (37ch fp32) -> LDS [px][42]
#pragma unroll
    for (int p = 0; p < 4; p++) {
        float* dst = &olds[(w*64 + p*16 + l16)*42];
#pragma unroll
        for (int t = 0; t < 3; t++) {
            if (t < 2 || quad < 2) {
                int cb = t*16 + quad*4;
                *(float2*)&dst[cb]   = make_float2(acc[p][t][0], acc[p][t][1]);
                *(float2*)&dst[cb+2] = make_float2(acc[p][t][2], acc[p][t][3]);
            }
        }
    }
    __syncthreads();

    // head: 1 px/thread. k0=(-.25,.25) k1=(.25,.25) k2=(-.25,-.25) k3=(.25,-.25)
    {
        int px = tid;
        int rr = px >> 6, xx = px & 63;
        const float* Wp = &olds[px*42];
        float base = Wp[36];
        float o0 = base, o1 = base, o2 = base, o3 = base;
#pragma unroll
        for (int j = 0; j < 12; j++) {
            float u  = Wp[2*j];
            float v  = Wp[2*j+1];
            float w1 = Wp[24+j];
            float s = 0.25f*(u+v);
            float d = 0.25f*(v-u);
            o0 += fmaxf(d, 0.f)*w1;
            o1 += fmaxf(s, 0.f)*w1;
            o2 += fmaxf(-s, 0.f)*w1;
            o3 += fmaxf(-d, 0.f)*w1;
        }
        int gy = trow*4 + rr, gx = x0 + xx;
        *(float2*)(outp + (size_t)(2*gy)*(2*WW) + 2*gx)   = make_float2(o0, o1);
        *(float2*)(outp + (size_t)(2*gy+1)*(2*WW) + 2*gx) = make_float2(o2, o3);
    }
}

extern "C" void kernel_launch(void* const* d_in, const int* in_sizes, int n_in,
                              void* d_out, int out_size, void* d_ws, size_t ws_size,
                              hipStream_t stream) {
    const float* x  = (const float*)d_in[0];
    const float* w1 = (const float*)d_in[1];
    const float* b1 = (const float*)d_in[2];
    const float* w2 = (const float*)d_in[3];
    const float* b2 = (const float*)d_in[4];
    const float* w3 = (const float*)d_in[5];
    const float* b3 = (const float*)d_in[6];
    const float* w4 = (const float*)d_in[7];
    const float* b4 = (const float*)d_in[8];
    const float* pa = (const float*)d_in[9];
    float* outp = (float*)d_out;

    char* ws = (char*)d_ws;
    f16* wpk = (f16*)ws;
    const f16* w1p = wpk;
    const f16* w2p = wpk + 2048;
    const f16* w3p = wpk + 2048 + 18432;
    const f16* w4p = wpk + 2048 + 18432 + 9216;
    f16* f1 = (f16*)(ws + 131072);
    f16* f2 = (f16*)(ws + 131072 + 66355200);
    f16* f3 = f1;   // alias: f1 dead by conv3 (stream-ordered)

    prepack_k<<<dim3(170), 256, 0, stream>>>(w1, w2, w3, w4, wpk);

    const int NT = 2025;   // (540/4) * (960/64)
    for (int b = 0; b < 4; b++) {
        conv1m_k<<<dim3(NT), 256, 0, stream>>>(x + (size_t)b*HWPIX, w1p, b1, pa, f1);
        convM_k<64,3><<<dim3(NT), 256, 0, stream>>>(f1, w2p, b2, pa, f2);
        convM_k<32,4><<<dim3(NT), 256, 0, stream>>>(f2, w3p, b3, pa, f3);
        conv4m_k<<<dim3(NT), 256, 0, stream>>>(f3, w4p, b4, outp + (size_t)b*4*HWPIX);
    }
}